// Round 10
// baseline (223.231 us; speedup 1.0000x reference)
//
#include <hip/hip_runtime.h>
#include <hip/hip_bf16.h>

#define MM 256
#define KK 4096
#define NN 32000
#define BN 64
#define BK 64
#define NT (KK / BK)   // 64 K-steps
#define GK 256         // K-floats per W fetch-group (1KB/row contiguous)
#define NG (KK / GK)   // 16 groups (4 K-steps each)

typedef __bf16 bf16x8 __attribute__((ext_vector_type(8)));
typedef float f32x4 __attribute__((ext_vector_type(4)));

__device__ __forceinline__ unsigned pk(float a, float b) {
    unsigned short lo = __builtin_bit_cast(unsigned short, __float2bfloat16(a));
    unsigned short hi = __builtin_bit_cast(unsigned short, __float2bfloat16(b));
    return (unsigned)lo | ((unsigned)hi << 16);
}

__device__ __forceinline__ void dma16(const unsigned short* g, unsigned short* l) {
    __builtin_amdgcn_global_load_lds(
        (const __attribute__((address_space(1))) unsigned int*)g,
        (__attribute__((address_space(3))) unsigned int*)l, 16, 0, 0);
}

// xb layout (verbatim R5): tile-major [t][row r][slot s], slot = 8 ushorts,
// pre-swizzled: slot s of row r holds x[r][t*64 + (s ^ (r&7))*8 .. +8).
__global__ void cvt_x_kernel(const float* __restrict__ x, unsigned short* __restrict__ xb) {
    int g = blockIdx.x * 256 + threadIdx.x;   // chunk id, 131072 total
    int t = g >> 11;
    int d = g & 2047;
    int r = d >> 3;
    int cs = d & 7;
    int c = cs ^ (r & 7);
    const float* s = x + r * KK + t * 64 + c * 8;
    float4 a = *(const float4*)s;
    float4 b = *(const float4*)(s + 4);
    uint4 p;
    p.x = pk(a.x, a.y); p.y = pk(a.z, a.w);
    p.z = pk(b.x, b.y); p.w = pk(b.z, b.w);
    *(uint4*)(xb + (size_t)g * 8) = p;
}

// C[m][n] = sum_k x[m][k] * w[n][k]. BM=256 (W fetched exactly once), BN=64,
// grid=500. 512 thr = 8 waves (4M x 2N). x: ws bf16 -> global_load_lds dbuf
// 2x32KB per K-step (R5 path). W: fetched in 4-step GROUPS — each row read
// as 1KB CONTIGUOUS (8 float4/thread) to cut DRAM activations 4x — held in
// regs ~3 steps, pk -> XOR-swizzled LDS group dbuf 2x32KB, consumed over 4
// MFMA steps. 128KB LDS -> 1 block/CU (R2 showed that's not the limiter).
template <bool XB>
__global__ __launch_bounds__(512, 2) void gemm_kernel(
    const unsigned short* __restrict__ xb, const float* __restrict__ xf,
    const float* __restrict__ w, float* __restrict__ out) {
    __shared__ unsigned short xs[2][16384];  // 2 x 32 KB (x K-step tiles)
    __shared__ unsigned short wt[2][16384];  // 2 x 32 KB (W 4-step groups)

    const int tid  = threadIdx.x;
    const int lane = tid & 63;
    const int wid  = tid >> 6;    // 0..7
    const int wm   = wid >> 1;    // 0..3 -> 64-row slice
    const int wn   = wid & 1;     // 0..1 -> 32-col slice
    const int l15  = lane & 15;
    const int lg   = lane >> 4;
    const int n0   = blockIdx.x * BN;

    // W group staging: thread -> row tid>>3 (0..63), 32 consecutive floats
    const int wrow  = tid >> 3;
    const int wpart = tid & 7;    // float offset wpart*32 within group
    const float* wsrc = w + (size_t)(n0 + wrow) * KK + wpart * 32;

    f32x4 acc[4][2];
#pragma unroll
    for (int i = 0; i < 4; ++i)
#pragma unroll
        for (int j = 0; j < 2; ++j) acc[i][j] = f32x4{0.f, 0.f, 0.f, 0.f};

    auto compute = [&](const unsigned short* wg, int pb, int q) {
        __builtin_amdgcn_s_setprio(1);
#pragma unroll
        for (int kf = 0; kf < 2; ++kf) {
            const int cW = q * 8 + kf * 4 + lg;   // chunk 0..31 within group
            uint4 bfr[2];
#pragma unroll
            for (int ni = 0; ni < 2; ++ni) {
                const int r = wn * 32 + ni * 16 + l15;   // r&15 == l15
                bfr[ni] = *(const uint4*)&wg[r * 256 + ((cW ^ l15) * 8)];
            }
            const int cX = kf * 4 + lg;
            uint4 af[4];
#pragma unroll
            for (int mi = 0; mi < 4; ++mi) {
                const int r = wm * 64 + mi * 16 + l15;   // r&7 == l15&7
                af[mi] = *(const uint4*)&xs[pb][r * 64 + ((cX ^ (l15 & 7)) * 8)];
            }
#pragma unroll
            for (int mi = 0; mi < 4; ++mi)
#pragma unroll
                for (int ni = 0; ni < 2; ++ni)
                    acc[mi][ni] = __builtin_amdgcn_mfma_f32_16x16x32_bf16(
                        __builtin_bit_cast(bf16x8, af[mi]),
                        __builtin_bit_cast(bf16x8, bfr[ni]), acc[mi][ni], 0, 0, 0);
        }
        __builtin_amdgcn_s_setprio(0);
    };

    if constexpr (!XB) {
        // correctness fallback (ws too small): direct global reads, no LDS
#pragma unroll 1
        for (int t = 0; t < KK / 32; ++t) {
            const int k = t * 32 + lg * 8;
            uint4 bfr[2];
#pragma unroll
            for (int ni = 0; ni < 2; ++ni) {
                const float* p = w + (size_t)(n0 + wn * 32 + ni * 16 + l15) * KK + k;
                float4 a0 = *(const float4*)p;
                float4 a1 = *(const float4*)(p + 4);
                bfr[ni].x = pk(a0.x, a0.y); bfr[ni].y = pk(a0.z, a0.w);
                bfr[ni].z = pk(a1.x, a1.y); bfr[ni].w = pk(a1.z, a1.w);
            }
#pragma unroll
            for (int mi = 0; mi < 4; ++mi) {
                const float* p = xf + (size_t)(wm * 64 + mi * 16 + l15) * KK + k;
                float4 a0 = *(const float4*)p;
                float4 a1 = *(const float4*)(p + 4);
                uint4 af;
                af.x = pk(a0.x, a0.y); af.y = pk(a0.z, a0.w);
                af.z = pk(a1.x, a1.y); af.w = pk(a1.z, a1.w);
#pragma unroll
                for (int ni = 0; ni < 2; ++ni)
                    acc[mi][ni] = __builtin_amdgcn_mfma_f32_16x16x32_bf16(
                        __builtin_bit_cast(bf16x8, af),
                        __builtin_bit_cast(bf16x8, bfr[ni]), acc[mi][ni], 0, 0, 0);
            }
        }
    } else {
        float4 wr[8];   // one W group slice: 32 consecutive floats of one row

        auto issueW = [&](int g) {
            const float* p = wsrc + g * GK;
#pragma unroll
            for (int i = 0; i < 8; ++i) wr[i] = *(const float4*)(p + i * 4);
        };
        auto stageW = [&](unsigned short* dst) {
#pragma unroll
            for (int j = 0; j < 4; ++j) {
                uint4 v;
                v.x = pk(wr[2 * j].x, wr[2 * j].y);
                v.y = pk(wr[2 * j].z, wr[2 * j].w);
                v.z = pk(wr[2 * j + 1].x, wr[2 * j + 1].y);
                v.w = pk(wr[2 * j + 1].z, wr[2 * j + 1].w);
                const int c = wpart * 4 + j;
                *(uint4*)&dst[wrow * 256 + ((c ^ (wrow & 15)) * 8)] = v;
            }
        };
        auto issue_dma = [&](int t, int pb) {
            // 4 rounds x 512 thr x 16B = 32 KB; wave-uniform base + lane*16B
#pragma unroll
            for (int j = 0; j < 4; ++j) {
                const unsigned short* gp =
                    xb + (size_t)t * 16384 + j * 4096 + wid * 512 + lane * 8;
                unsigned short* lp = &xs[pb][j * 4096 + wid * 512];
                dma16(gp, lp);
            }
        };

        // prologue: W(0) -> regs -> wt[0]; xdma(0) in flight into xs[0]
        issueW(0);
        issue_dma(0, 0);
        stageW(&wt[0][0]);   // reg-dep drains W(0), keeps xdma(0)
        __builtin_amdgcn_sched_barrier(0);
        asm volatile("s_waitcnt lgkmcnt(0)" ::: "memory");
        __builtin_amdgcn_sched_barrier(0);
        __builtin_amdgcn_s_barrier();   // wt[0] published

#pragma unroll 1
        for (int tt = 0; tt < NT; tt += 4) {
            const int g = tt >> 2;
#pragma unroll
            for (int q = 0; q < 4; ++q) {
                const int t  = tt + q;
                const int pb = q & 1;   // tt multiple of 4 -> t&1 == q&1
                if (q == 3) stageW(&wt[(g + 1) & 1][0]);  // W(g+1) regs (drained since q==1)
                __builtin_amdgcn_sched_barrier(0);
                asm volatile("s_waitcnt vmcnt(0)" ::: "memory");   // xdma(t) done (issued 1 step ago)
                asm volatile("s_waitcnt lgkmcnt(0)" ::: "memory");
                __builtin_amdgcn_sched_barrier(0);
                __builtin_amdgcn_s_barrier();   // xs[pb] (+ wt if staged) published
                const int tn = (t + 1 < NT) ? t + 1 : NT - 1;
                issue_dma(tn, pb ^ 1);          // safe: compute(t-1) done block-wide
                if (q == 0) {
                    const int gn = (g + 1 < NG) ? g + 1 : NG - 1;
                    issueW(gn);                 // 1KB/row contiguous burst
                }
                __builtin_amdgcn_sched_barrier(0);
                compute(&wt[g & 1][0], pb, q);
            }
        }
        asm volatile("s_waitcnt vmcnt(0)" ::: "memory");  // drain tail junk
    }

    // epilogue: per 16x16 tile, col = lane&15, row = (lane>>4)*4 + v
#pragma unroll
    for (int mi = 0; mi < 4; ++mi)
#pragma unroll
        for (int ni = 0; ni < 2; ++ni) {
            const int rowb = wm * 64 + mi * 16 + lg * 4;
            const int col  = n0 + wn * 32 + ni * 16 + l15;
#pragma unroll
            for (int v = 0; v < 4; ++v)
                out[(size_t)(rowb + v) * NN + col] = acc[mi][ni][v];
        }
}

extern "C" void kernel_launch(void* const* d_in, const int* in_sizes, int n_in,
                              void* d_out, int out_size, void* d_ws, size_t ws_size,
                              hipStream_t stream) {
    const float* x = (const float*)d_in[0];
    const float* w = (const float*)d_in[1];
    float* out = (float*)d_out;
    unsigned short* xb = (unsigned short*)d_ws;

    if (ws_size >= (size_t)MM * KK * sizeof(unsigned short)) {
        cvt_x_kernel<<<512, 256, 0, stream>>>(x, xb);
        gemm_kernel<true><<<NN / BN, 512, 0, stream>>>(xb, x, w, out);
    } else {
        gemm_kernel<false><<<NN / BN, 512, 0, stream>>>(nullptr, x, w, out);
    }
}